// Round 4
// baseline (1640.297 us; speedup 1.0000x reference)
//
#include <hip/hip_runtime.h>

#define T_SEQ 188
#define NB    256
#define NIN   128
#define NH    256
#define ZSTR  264   // 128 x + 128 own-h + 8 pad shorts; 528 B row stride

typedef __attribute__((ext_vector_type(8))) short s16x8;
typedef __attribute__((ext_vector_type(4))) short s16x4;
typedef __attribute__((ext_vector_type(4))) float f32x4;

__device__ __forceinline__ short f2bf(float f) {
    union { float f; unsigned u; } v; v.f = f;
    unsigned r = v.u + 0x7fffu + ((v.u >> 16) & 1u);   // RNE
    return (short)(r >> 16);
}
__device__ __forceinline__ float sigf(float x) {
    return __builtin_amdgcn_rcpf(1.0f + __expf(-x));
}
__device__ __forceinline__ float tanh_(float x) {
    return 1.0f - 2.0f * __builtin_amdgcn_rcpf(__expf(2.0f * x) + 1.0f);
}

// WG b: dir = b>>5, hidden-half hh = (b>>4)&1, batch-tile bt = b&15. Partner = b^16.
// 8 waves; wave w owns hidden units [hh*128+16w, +16) for all 4 gates; 48 bf16
// A-fragments (192 VGPRs) register-resident for the whole sequence.
// Exchange: self-flagging tagged words in IC-coherent d_ws ping-pong slots.
//   word = (bf16(h) << 16) | (step & 3). Tag bits are the bits bf16 discards.
//   Slot = step & 1 (overwrite is 2 steps apart -> race-free by program order).
//   Consumer polls its own B-fragment words directly: poll == data load.
__global__ __launch_bounds__(512, 2) void lstm_persist(
    const float* __restrict__ x,
    const float* __restrict__ w_ih_f, const float* __restrict__ w_hh_f,
    const float* __restrict__ b_ih_f, const float* __restrict__ b_hh_f,
    const float* __restrict__ w_ih_b, const float* __restrict__ w_hh_b,
    const float* __restrict__ b_ih_b, const float* __restrict__ b_hh_b,
    float* __restrict__ out, unsigned long long* __restrict__ xchg)
{
    const int b  = blockIdx.x;
    const int d  = b >> 5;
    const int hh = (b >> 4) & 1;
    const int bt = b & 15;
    const int pb = b ^ 16;
    const int po = 1 - hh;

    const float* w_ih = d ? w_ih_b : w_ih_f;
    const float* w_hh = d ? w_hh_b : w_hh_f;
    const float* b_ih = d ? b_ih_b : b_ih_f;
    const float* b_hh = d ? b_hh_b : b_hh_f;

    const int tid = threadIdx.x;
    const int w   = tid >> 6;
    const int l   = tid & 63;
    const int lg  = l >> 4;
    const int lb  = l & 15;
    const int hbase = hh * 128 + 16 * w;

    __shared__ short Z[2][16][ZSTR];     // row: [0,128)=x_t, [128,256)=own h-half
    __shared__ float biasL[8][4][16];

    const int off_x   = lg * 8;
    const int off_own = NIN + lg * 8;

    // ---- weights -> registers as 16x16x32 A-fragments (lane: A[lb][8*lg+e]) ----
    // K-tile order: 0..3 = x, 4..7 = own h-half, 8..11 = partner h-half
    s16x8 wf[4][12];
    #pragma unroll
    for (int G = 0; G < 4; ++G) {
        const int gc = G * 256 + hbase + lb;
        #pragma unroll
        for (int kkidx = 0; kkidx < 12; ++kkidx) {
            const int kglob = (kkidx < 4)  ? (32 * kkidx + 8 * lg)
                            : (kkidx < 8)  ? (NIN + hh * 128 + 32 * (kkidx - 4) + 8 * lg)
                                           : (NIN + po * 128 + 32 * (kkidx - 8) + 8 * lg);
            const float* src = (kglob < NIN) ? (w_ih + (size_t)gc * NIN + kglob)
                                             : (w_hh + (size_t)gc * NH + (kglob - NIN));
            float4 a  = *(const float4*)(src);
            float4 b2 = *(const float4*)(src + 4);
            s16x8 tv;
            tv[0] = f2bf(a.x);  tv[1] = f2bf(a.y);  tv[2] = f2bf(a.z);  tv[3] = f2bf(a.w);
            tv[4] = f2bf(b2.x); tv[5] = f2bf(b2.y); tv[6] = f2bf(b2.z); tv[7] = f2bf(b2.w);
            wf[G][kkidx] = tv;
        }
    }

    // ---- biases -> LDS
    {
        const int G = lb >> 2, r = lb & 3;
        const int gcr = G * 256 + hbase + 4 * lg + r;
        biasL[w][G][4 * lg + r] = b_ih[gcr] + b_hh[gcr];
    }

    const int srow = tid >> 5;
    const int sk4  = (tid & 31) * 4;

    // ---- init Z[0]: own h = 0, x = x[t0]
    {
        s16x4 zz; zz[0] = 0; zz[1] = 0; zz[2] = 0; zz[3] = 0;
        *(s16x4*)&Z[0][srow][NIN + (tid & 31) * 4] = zz;
        const int t0 = d ? (T_SEQ - 1) : 0;
        float4 xv0 = *(const float4*)(x + ((size_t)(t0 * NB + bt * 16 + srow)) * NIN + sk4);
        s16x4 xp;
        xp[0] = f2bf(xv0.x); xp[1] = f2bf(xv0.y); xp[2] = f2bf(xv0.z); xp[3] = f2bf(xv0.w);
        *(s16x4*)&Z[0][srow][sk4] = xp;
    }
    float cst[4] = {0.f, 0.f, 0.f, 0.f};
    __syncthreads();

    float* outp = out + (size_t)(bt * 16) * 512 + d * 256 + hbase + 4 * lg;

    for (int s = 0; s < T_SEQ; ++s) {
        const int p = s & 1;
        const int t = d ? (T_SEQ - 1 - s) : s;

        // ---- issue partner polling loads (slot = (s-1)&1 = p^1); poll == data
        unsigned long long pv[16];
        const unsigned long long* pbase =
            xchg + (((size_t)(pb * 2 + (p ^ 1)) * 16 + lb) * 64) + 4 * lg;
        if (s > 0) {
            #pragma unroll
            for (int kk = 0; kk < 4; ++kk)
                #pragma unroll
                for (int j = 0; j < 4; ++j)
                    pv[4 * kk + j] = __hip_atomic_load(pbase + 16 * kk + j,
                        __ATOMIC_RELAXED, __HIP_MEMORY_SCOPE_AGENT);
        }

        // ---- prefetch next x
        float4 xv;
        const bool havex = (s + 1 < T_SEQ);
        if (havex) {
            const int tn = d ? (T_SEQ - 2 - s) : (s + 1);
            xv = *(const float4*)(x + ((size_t)(tn * NB + bt * 16 + srow)) * NIN + sk4);
        }

        f32x4 acc[4];
        #pragma unroll
        for (int G = 0; G < 4; ++G)
            acc[G] = *(const f32x4*)&biasL[w][G][4 * lg];

        const short* zrow = &Z[p][lb][0];

        // ---- phase B: x + own-half tiles from LDS (partner loads in flight)
        #pragma unroll
        for (int kk = 0; kk < 4; ++kk) {
            s16x8 bfv = *(const s16x8*)(zrow + off_x + 32 * kk);
            acc[0] = __builtin_amdgcn_mfma_f32_16x16x32_bf16(wf[0][kk], bfv, acc[0], 0, 0, 0);
            acc[1] = __builtin_amdgcn_mfma_f32_16x16x32_bf16(wf[1][kk], bfv, acc[1], 0, 0, 0);
            acc[2] = __builtin_amdgcn_mfma_f32_16x16x32_bf16(wf[2][kk], bfv, acc[2], 0, 0, 0);
            acc[3] = __builtin_amdgcn_mfma_f32_16x16x32_bf16(wf[3][kk], bfv, acc[3], 0, 0, 0);
        }
        #pragma unroll
        for (int kk = 0; kk < 4; ++kk) {
            s16x8 bfv = *(const s16x8*)(zrow + off_own + 32 * kk);
            acc[0] = __builtin_amdgcn_mfma_f32_16x16x32_bf16(wf[0][4 + kk], bfv, acc[0], 0, 0, 0);
            acc[1] = __builtin_amdgcn_mfma_f32_16x16x32_bf16(wf[1][4 + kk], bfv, acc[1], 0, 0, 0);
            acc[2] = __builtin_amdgcn_mfma_f32_16x16x32_bf16(wf[2][4 + kk], bfv, acc[2], 0, 0, 0);
            acc[3] = __builtin_amdgcn_mfma_f32_16x16x32_bf16(wf[3][4 + kk], bfv, acc[3], 0, 0, 0);
        }

        // ---- phase D: per-tile tag-check/retry, convert, MFMA
        if (s > 0) {
            const unsigned long long want = (unsigned long long)((s - 1) & 3);
            #pragma unroll
            for (int kk = 0; kk < 4; ++kk) {
                while (true) {
                    bool ok = true;
                    #pragma unroll
                    for (int j = 0; j < 4; ++j) {
                        const unsigned long long v = pv[4 * kk + j];
                        ok = ok && ((v & 3ull) == want) && (((v >> 32) & 3ull) == want);
                    }
                    if (ok) break;
                    #pragma unroll
                    for (int j = 0; j < 4; ++j)
                        pv[4 * kk + j] = __hip_atomic_load(pbase + 16 * kk + j,
                            __ATOMIC_RELAXED, __HIP_MEMORY_SCOPE_AGENT);
                }
                s16x8 bfv;
                #pragma unroll
                for (int j = 0; j < 4; ++j) {
                    const unsigned long long v = pv[4 * kk + j];
                    bfv[2 * j]     = (short)((v >> 16) & 0xffffull);
                    bfv[2 * j + 1] = (short)(v >> 48);
                }
                acc[0] = __builtin_amdgcn_mfma_f32_16x16x32_bf16(wf[0][8 + kk], bfv, acc[0], 0, 0, 0);
                acc[1] = __builtin_amdgcn_mfma_f32_16x16x32_bf16(wf[1][8 + kk], bfv, acc[1], 0, 0, 0);
                acc[2] = __builtin_amdgcn_mfma_f32_16x16x32_bf16(wf[2][8 + kk], bfv, acc[2], 0, 0, 0);
                acc[3] = __builtin_amdgcn_mfma_f32_16x16x32_bf16(wf[3][8 + kk], bfv, acc[3], 0, 0, 0);
            }
        }

        // ---- gates -> c,h (lane: 4 hidden units, batch col lb)
        float4 hout;
        s16x4 hbf;
        #pragma unroll
        for (int r = 0; r < 4; ++r) {
            const float iv = sigf(acc[0][r]);
            const float fv = sigf(acc[1][r]);
            const float gv = tanh_(acc[2][r]);
            const float ov = sigf(acc[3][r]);
            const float c  = fv * cst[r] + iv * gv;
            cst[r] = c;
            const float h = ov * tanh_(c);
            (&hout.x)[r] = h;
            hbf[r] = f2bf(h);
        }

        // ---- publish own h immediately (tagged, slot s&1): the critical store
        {
            const unsigned tag = (unsigned)(s & 3);
            const unsigned w0 = ((unsigned)(unsigned short)hbf[0] << 16) | tag;
            const unsigned w1 = ((unsigned)(unsigned short)hbf[1] << 16) | tag;
            const unsigned w2 = ((unsigned)(unsigned short)hbf[2] << 16) | tag;
            const unsigned w3 = ((unsigned)(unsigned short)hbf[3] << 16) | tag;
            const unsigned long long q0 = (unsigned long long)w0 | ((unsigned long long)w1 << 32);
            const unsigned long long q1 = (unsigned long long)w2 | ((unsigned long long)w3 << 32);
            unsigned long long* mybase =
                xchg + (((size_t)(b * 2 + p) * 16 + lb) * 64) + 8 * w + 2 * lg;
            __hip_atomic_store(mybase,     q0, __ATOMIC_RELAXED, __HIP_MEMORY_SCOPE_AGENT);
            __hip_atomic_store(mybase + 1, q1, __ATOMIC_RELAXED, __HIP_MEMORY_SCOPE_AGENT);
        }

        // ---- own h + next x -> next Z buffer; h -> out
        *(s16x4*)&Z[p ^ 1][lb][NIN + 16 * w + 4 * lg] = hbf;
        if (havex) {
            s16x4 xp;
            xp[0] = f2bf(xv.x); xp[1] = f2bf(xv.y); xp[2] = f2bf(xv.z); xp[3] = f2bf(xv.w);
            *(s16x4*)&Z[p ^ 1][srow][sk4] = xp;
        }
        *(f32x4*)(outp + (size_t)t * NB * 512 + lb * 512) = *(f32x4*)&hout;

        __syncthreads();   // Z[p^1] ready for next step
    }
}

extern "C" void kernel_launch(void* const* d_in, const int* in_sizes, int n_in,
                              void* d_out, int out_size, void* d_ws, size_t ws_size,
                              hipStream_t stream) {
    const float* x      = (const float*)d_in[0];
    const float* w_ih_f = (const float*)d_in[1];
    const float* w_hh_f = (const float*)d_in[2];
    const float* b_ih_f = (const float*)d_in[3];
    const float* b_hh_f = (const float*)d_in[4];
    const float* w_ih_b = (const float*)d_in[5];
    const float* w_hh_b = (const float*)d_in[6];
    const float* b_ih_b = (const float*)d_in[7];
    const float* b_hh_b = (const float*)d_in[8];
    float* out = (float*)d_out;
    unsigned long long* xchg = (unsigned long long*)d_ws;

    // 0x03 byte pattern -> every u32 has tag bits = 3; tag 3 is only expected
    // at steps where real data provably already overwrote it. Replay-safe.
    hipMemsetAsync(d_ws, 0x03, (size_t)128 * 16 * 64 * 8, stream);  // 1 MiB

    lstm_persist<<<dim3(64), dim3(512), 0, stream>>>(
        x, w_ih_f, w_hh_f, b_ih_f, b_hh_f, w_ih_b, w_hh_b, b_ih_b, b_hh_b,
        out, xchg);
}

// Round 6
// 1152.433 us; speedup vs baseline: 1.4233x; 1.4233x over previous
//
#include <hip/hip_runtime.h>

#define T_SEQ 188
#define NB    256
#define NIN   128
#define NH    256
#define ZSTR  264   // 128 x + 128 own-h + 8 pad shorts; 528 B row stride

typedef __attribute__((ext_vector_type(8))) short s16x8;
typedef __attribute__((ext_vector_type(4))) short s16x4;
typedef __attribute__((ext_vector_type(4))) float f32x4;
typedef __attribute__((ext_vector_type(4))) unsigned u32x4;

__device__ __forceinline__ short f2bf(float f) {
    union { float f; unsigned u; } v; v.f = f;
    unsigned r = v.u + 0x7fffu + ((v.u >> 16) & 1u);   // RNE
    return (short)(r >> 16);
}
__device__ __forceinline__ float sigf(float x) {
    return __builtin_amdgcn_rcpf(1.0f + __expf(-x));
}
__device__ __forceinline__ float tanh_(float x) {
    return 1.0f - 2.0f * __builtin_amdgcn_rcpf(__expf(2.0f * x) + 1.0f);
}
__device__ __forceinline__ bool tagok(u32x4 a, u32x4 b, unsigned want) {
    unsigned t = ((a[0] & 3u) ^ want) | ((a[1] & 3u) ^ want)
               | ((a[2] & 3u) ^ want) | ((a[3] & 3u) ^ want)
               | ((b[0] & 3u) ^ want) | ((b[1] & 3u) ^ want)
               | ((b[2] & 3u) ^ want) | ((b[3] & 3u) ^ want);
    return t == 0u;
}

// WG b: dir=b>>5, hidden-half hh=(b>>4)&1, batch-tile bt=b&15. Partner = b^16
// (same XCD under round-robin — verified at runtime via XCC_ID handshake;
// falls back to IC-coherent sc0sc1 protocol if the mapping differs).
// Exchange: self-flagging tagged u32 words, word = (bf16(h)<<16) | (step&3),
// ping-pong slot = step&1. FAST path (same XCD): publish sc0 (write-through to
// the shared L2); consume with acquire-fence (vL1 buffer_inv) + sc0 loads —
// L1 cannot serve stale data, L2 is the single coherence point. SLOW path:
// sc0 sc1 both sides (IC-coherent, R4-proven). Poll IS the data load.
__global__ __launch_bounds__(512, 2) void lstm_persist(
    const float* __restrict__ x,
    const float* __restrict__ w_ih_f, const float* __restrict__ w_hh_f,
    const float* __restrict__ b_ih_f, const float* __restrict__ b_hh_f,
    const float* __restrict__ w_ih_b, const float* __restrict__ w_hh_b,
    const float* __restrict__ b_ih_b, const float* __restrict__ b_hh_b,
    float* __restrict__ out, unsigned* __restrict__ hsbuf,
    unsigned* __restrict__ xchg)
{
    const int b  = blockIdx.x;
    const int d  = b >> 5;
    const int hh = (b >> 4) & 1;
    const int bt = b & 15;
    const int pb = b ^ 16;
    const int po = 1 - hh;

    const float* w_ih = d ? w_ih_b : w_ih_f;
    const float* w_hh = d ? w_hh_b : w_hh_f;
    const float* b_ih = d ? b_ih_b : b_ih_f;
    const float* b_hh = d ? b_hh_b : b_hh_f;

    const int tid = threadIdx.x;
    const int w   = tid >> 6;
    const int l   = tid & 63;
    const int lg  = l >> 4;
    const int lb  = l & 15;
    const int hbase = hh * 128 + 16 * w;

    __shared__ short Z[2][16][ZSTR];     // row: [0,128)=x_t, [128,256)=own h-half
    __shared__ float biasL[8][4][16];
    __shared__ int fastLds;

    const int off_x   = lg * 8;
    const int off_own = NIN + lg * 8;

    // ---- one-time XCD handshake (agent-scope words in d_ws; memset to 0) ----
    if (tid == 0) {
        unsigned xcc;
        asm volatile("s_getreg_b32 %0, hwreg(20, 0, 4)" : "=s"(xcc));  // HW_REG_XCC_ID
        __hip_atomic_store(&hsbuf[b * 16], xcc + 1u,
                           __ATOMIC_RELAXED, __HIP_MEMORY_SCOPE_AGENT);
        unsigned pid;
        do {
            pid = __hip_atomic_load(&hsbuf[pb * 16],
                                    __ATOMIC_RELAXED, __HIP_MEMORY_SCOPE_AGENT);
        } while (pid == 0u);
        fastLds = (pid == xcc + 1u);
    }

    // ---- weights -> registers as 16x16x32 A-fragments (lane: A[lb][8*lg+e]) ----
    // K-tile order: 0..3 = x, 4..7 = own h-half, 8..11 = partner h-half
    s16x8 wf[4][12];
    #pragma unroll
    for (int G = 0; G < 4; ++G) {
        const int gc = G * 256 + hbase + lb;
        #pragma unroll
        for (int kkidx = 0; kkidx < 12; ++kkidx) {
            const int kglob = (kkidx < 4)  ? (32 * kkidx + 8 * lg)
                            : (kkidx < 8)  ? (NIN + hh * 128 + 32 * (kkidx - 4) + 8 * lg)
                                           : (NIN + po * 128 + 32 * (kkidx - 8) + 8 * lg);
            const float* src = (kglob < NIN) ? (w_ih + (size_t)gc * NIN + kglob)
                                             : (w_hh + (size_t)gc * NH + (kglob - NIN));
            float4 a  = *(const float4*)(src);
            float4 b2 = *(const float4*)(src + 4);
            s16x8 tv;
            tv[0] = f2bf(a.x);  tv[1] = f2bf(a.y);  tv[2] = f2bf(a.z);  tv[3] = f2bf(a.w);
            tv[4] = f2bf(b2.x); tv[5] = f2bf(b2.y); tv[6] = f2bf(b2.z); tv[7] = f2bf(b2.w);
            wf[G][kkidx] = tv;
        }
    }

    // ---- biases -> LDS
    {
        const int G = lb >> 2, r = lb & 3;
        const int gcr = G * 256 + hbase + 4 * lg + r;
        biasL[w][G][4 * lg + r] = b_ih[gcr] + b_hh[gcr];
    }

    const int srow = tid >> 5;
    const int sk4  = (tid & 31) * 4;

    // ---- init Z[0]: own h = 0, x = x[t0]
    {
        s16x4 zz; zz[0] = 0; zz[1] = 0; zz[2] = 0; zz[3] = 0;
        *(s16x4*)&Z[0][srow][NIN + (tid & 31) * 4] = zz;
        const int t0 = d ? (T_SEQ - 1) : 0;
        float4 xv0 = *(const float4*)(x + ((size_t)(t0 * NB + bt * 16 + srow)) * NIN + sk4);
        s16x4 xp;
        xp[0] = f2bf(xv0.x); xp[1] = f2bf(xv0.y); xp[2] = f2bf(xv0.z); xp[3] = f2bf(xv0.w);
        *(s16x4*)&Z[0][srow][sk4] = xp;
    }
    float cst[4] = {0.f, 0.f, 0.f, 0.f};
    __syncthreads();
    const bool fast = (fastLds != 0);

    float* outp = out + (size_t)(bt * 16) * 512 + d * 256 + hbase + 4 * lg;

#define RELOAD_FAST(a_, b_, addr_)                                                       \
    asm volatile("global_load_dwordx4 %0, %2, off sc0\n\t"                               \
                 "global_load_dwordx4 %1, %2, off offset:16 sc0\n\t"                     \
                 "s_waitcnt vmcnt(0)"                                                    \
                 : "=&v"(a_), "=&v"(b_) : "v"(addr_) : "memory")
#define RELOAD_SLOW(a_, b_, addr_)                                                       \
    asm volatile("global_load_dwordx4 %0, %2, off sc0 sc1\n\t"                           \
                 "global_load_dwordx4 %1, %2, off offset:16 sc0 sc1\n\t"                 \
                 "s_waitcnt vmcnt(0)"                                                    \
                 : "=&v"(a_), "=&v"(b_) : "v"(addr_) : "memory")

#define DOTILE(kk_, qa_, qb_)                                                            \
    do {                                                                                 \
        const unsigned* taddr = pbase + 32 * kk_;                                        \
        unsigned tries = 0;                                                              \
        while (!tagok(qa_, qb_, want)) {                                                 \
            ++tries;                                                                     \
            if (fast) {                                                                  \
                __builtin_amdgcn_fence(__ATOMIC_ACQUIRE, "agent");                       \
                if ((tries & 16384u) != 0u) { RELOAD_SLOW(qa_, qb_, taddr); }            \
                else                        { RELOAD_FAST(qa_, qb_, taddr); }            \
            } else {                                                                     \
                RELOAD_SLOW(qa_, qb_, taddr);                                            \
            }                                                                            \
        }                                                                                \
        s16x8 bfv;                                                                       \
        bfv[0] = (short)(qa_[0] >> 16); bfv[1] = (short)(qa_[1] >> 16);                  \
        bfv[2] = (short)(qa_[2] >> 16); bfv[3] = (short)(qa_[3] >> 16);                  \
        bfv[4] = (short)(qb_[0] >> 16); bfv[5] = (short)(qb_[1] >> 16);                  \
        bfv[6] = (short)(qb_[2] >> 16); bfv[7] = (short)(qb_[3] >> 16);                  \
        acc[0] = __builtin_amdgcn_mfma_f32_16x16x32_bf16(wf[0][8 + kk_], bfv, acc[0], 0, 0, 0); \
        acc[1] = __builtin_amdgcn_mfma_f32_16x16x32_bf16(wf[1][8 + kk_], bfv, acc[1], 0, 0, 0); \
        acc[2] = __builtin_amdgcn_mfma_f32_16x16x32_bf16(wf[2][8 + kk_], bfv, acc[2], 0, 0, 0); \
        acc[3] = __builtin_amdgcn_mfma_f32_16x16x32_bf16(wf[3][8 + kk_], bfv, acc[3], 0, 0, 0); \
    } while (0)

    for (int s = 0; s < T_SEQ; ++s) {
        const int p = s & 1;
        const int t = d ? (T_SEQ - 1 - s) : s;

        // ---- issue 8 polling dwordx4 loads for partner h(s-1); poll == data
        const unsigned* pbase =
            xchg + ((size_t)(pb * 2 + (p ^ 1)) * 16 + lb) * 128 + 8 * lg;
        u32x4 q0, q1, q2, q3, q4, q5, q6, q7;
        if (s > 0) {
            if (fast) {
                // invalidate vL1 so the sc0 polls below must read the shared L2
                __builtin_amdgcn_fence(__ATOMIC_ACQUIRE, "agent");
                asm volatile(
                    "global_load_dwordx4 %0, %8, off sc0\n\t"
                    "global_load_dwordx4 %1, %8, off offset:16 sc0\n\t"
                    "global_load_dwordx4 %2, %8, off offset:128 sc0\n\t"
                    "global_load_dwordx4 %3, %8, off offset:144 sc0\n\t"
                    "global_load_dwordx4 %4, %8, off offset:256 sc0\n\t"
                    "global_load_dwordx4 %5, %8, off offset:272 sc0\n\t"
                    "global_load_dwordx4 %6, %8, off offset:384 sc0\n\t"
                    "global_load_dwordx4 %7, %8, off offset:400 sc0"
                    : "=&v"(q0), "=&v"(q1), "=&v"(q2), "=&v"(q3),
                      "=&v"(q4), "=&v"(q5), "=&v"(q6), "=&v"(q7)
                    : "v"(pbase));
            } else {
                asm volatile(
                    "global_load_dwordx4 %0, %8, off sc0 sc1\n\t"
                    "global_load_dwordx4 %1, %8, off offset:16 sc0 sc1\n\t"
                    "global_load_dwordx4 %2, %8, off offset:128 sc0 sc1\n\t"
                    "global_load_dwordx4 %3, %8, off offset:144 sc0 sc1\n\t"
                    "global_load_dwordx4 %4, %8, off offset:256 sc0 sc1\n\t"
                    "global_load_dwordx4 %5, %8, off offset:272 sc0 sc1\n\t"
                    "global_load_dwordx4 %6, %8, off offset:384 sc0 sc1\n\t"
                    "global_load_dwordx4 %7, %8, off offset:400 sc0 sc1"
                    : "=&v"(q0), "=&v"(q1), "=&v"(q2), "=&v"(q3),
                      "=&v"(q4), "=&v"(q5), "=&v"(q6), "=&v"(q7)
                    : "v"(pbase));
            }
        }

        // ---- prefetch next x
        float4 xv;
        const bool havex = (s + 1 < T_SEQ);
        if (havex) {
            const int tn = d ? (T_SEQ - 2 - s) : (s + 1);
            xv = *(const float4*)(x + ((size_t)(tn * NB + bt * 16 + srow)) * NIN + sk4);
        }

        f32x4 acc[4];
        #pragma unroll
        for (int G = 0; G < 4; ++G)
            acc[G] = *(const f32x4*)&biasL[w][G][4 * lg];

        const short* zrow = &Z[p][lb][0];

        // ---- phase B: x + own-half tiles from LDS (partner loads in flight)
        #pragma unroll
        for (int kk = 0; kk < 4; ++kk) {
            s16x8 bfv = *(const s16x8*)(zrow + off_x + 32 * kk);
            acc[0] = __builtin_amdgcn_mfma_f32_16x16x32_bf16(wf[0][kk], bfv, acc[0], 0, 0, 0);
            acc[1] = __builtin_amdgcn_mfma_f32_16x16x32_bf16(wf[1][kk], bfv, acc[1], 0, 0, 0);
            acc[2] = __builtin_amdgcn_mfma_f32_16x16x32_bf16(wf[2][kk], bfv, acc[2], 0, 0, 0);
            acc[3] = __builtin_amdgcn_mfma_f32_16x16x32_bf16(wf[3][kk], bfv, acc[3], 0, 0, 0);
        }
        #pragma unroll
        for (int kk = 0; kk < 4; ++kk) {
            s16x8 bfv = *(const s16x8*)(zrow + off_own + 32 * kk);
            acc[0] = __builtin_amdgcn_mfma_f32_16x16x32_bf16(wf[0][4 + kk], bfv, acc[0], 0, 0, 0);
            acc[1] = __builtin_amdgcn_mfma_f32_16x16x32_bf16(wf[1][4 + kk], bfv, acc[1], 0, 0, 0);
            acc[2] = __builtin_amdgcn_mfma_f32_16x16x32_bf16(wf[2][4 + kk], bfv, acc[2], 0, 0, 0);
            acc[3] = __builtin_amdgcn_mfma_f32_16x16x32_bf16(wf[3][4 + kk], bfv, acc[3], 0, 0, 0);
        }

        // ---- phase D: wait loads, anchor values, tag-check per tile, MFMA
        if (s > 0) {
            asm volatile("s_waitcnt vmcnt(0)" ::: "memory");
            asm volatile("" : "+v"(q0), "+v"(q1), "+v"(q2), "+v"(q3),
                             "+v"(q4), "+v"(q5), "+v"(q6), "+v"(q7));
            const unsigned want = (unsigned)((s - 1) & 3);
            DOTILE(0, q0, q1);
            DOTILE(1, q2, q3);
            DOTILE(2, q4, q5);
            DOTILE(3, q6, q7);
        }

        // ---- gates -> c,h (lane: 4 hidden units, batch col lb)
        float4 hout;
        s16x4 hbf;
        #pragma unroll
        for (int r = 0; r < 4; ++r) {
            const float iv = sigf(acc[0][r]);
            const float fv = sigf(acc[1][r]);
            const float gv = tanh_(acc[2][r]);
            const float ov = sigf(acc[3][r]);
            const float c  = fv * cst[r] + iv * gv;
            cst[r] = c;
            const float h = ov * tanh_(c);
            (&hout.x)[r] = h;
            hbf[r] = f2bf(h);
        }

        // ---- publish own h immediately (tagged words, slot s&1)
        {
            const unsigned tag = (unsigned)(s & 3);
            u32x4 hq;
            hq[0] = ((unsigned)(unsigned short)hbf[0] << 16) | tag;
            hq[1] = ((unsigned)(unsigned short)hbf[1] << 16) | tag;
            hq[2] = ((unsigned)(unsigned short)hbf[2] << 16) | tag;
            hq[3] = ((unsigned)(unsigned short)hbf[3] << 16) | tag;
            unsigned* mybase =
                xchg + ((size_t)(b * 2 + p) * 16 + lb) * 128 + 16 * w + 4 * lg;
            if (fast)
                asm volatile("global_store_dwordx4 %0, %1, off sc0"
                             :: "v"(mybase), "v"(hq) : "memory");
            else
                asm volatile("global_store_dwordx4 %0, %1, off sc0 sc1"
                             :: "v"(mybase), "v"(hq) : "memory");
        }

        // ---- own h + next x -> next Z buffer; h -> out
        *(s16x4*)&Z[p ^ 1][lb][NIN + 16 * w + 4 * lg] = hbf;
        if (havex) {
            s16x4 xp;
            xp[0] = f2bf(xv.x); xp[1] = f2bf(xv.y); xp[2] = f2bf(xv.z); xp[3] = f2bf(xv.w);
            *(s16x4*)&Z[p ^ 1][srow][sk4] = xp;
        }
        *(f32x4*)(outp + (size_t)t * NB * 512 + lb * 512) = *(f32x4*)&hout;

        __syncthreads();   // drains vmcnt (sc0 stores complete at L2); Z[p^1] ready
    }
#undef RELOAD_FAST
#undef RELOAD_SLOW
#undef DOTILE
}

extern "C" void kernel_launch(void* const* d_in, const int* in_sizes, int n_in,
                              void* d_out, int out_size, void* d_ws, size_t ws_size,
                              hipStream_t stream) {
    const float* x      = (const float*)d_in[0];
    const float* w_ih_f = (const float*)d_in[1];
    const float* w_hh_f = (const float*)d_in[2];
    const float* b_ih_f = (const float*)d_in[3];
    const float* b_hh_f = (const float*)d_in[4];
    const float* w_ih_b = (const float*)d_in[5];
    const float* w_hh_b = (const float*)d_in[6];
    const float* b_ih_b = (const float*)d_in[7];
    const float* b_hh_b = (const float*)d_in[8];
    float* out = (float*)d_out;

    unsigned* hsbuf = (unsigned*)d_ws;                        // 4 KB handshake
    unsigned* xchg  = (unsigned*)((char*)d_ws + 4096);        // 1 MiB exchange

    hipMemsetAsync(hsbuf, 0, 4096, stream);
    // 0x03 pattern: tag bits = 3 everywhere; a tag-3 false positive is
    // impossible before real data overwrote the word (monotonic per-location
    // history, proven for s=4 by the consumer's own s=2 pass). Replay-safe.
    hipMemsetAsync(xchg, 0x03, (size_t)64 * 2 * 16 * 512, stream);

    lstm_persist<<<dim3(64), dim3(512), 0, stream>>>(
        x, w_ih_f, w_hh_f, b_ih_f, b_hh_f, w_ih_b, w_hh_b, b_ih_b, b_hh_b,
        out, hsbuf, xchg);
}